// Round 1
// baseline (5930.252 us; speedup 1.0000x reference)
//
#include <hip/hip_runtime.h>

#define B_ 8192
#define S_ 256
#define D_ 32
#define H_ 256
#define E_ 32
#define BT 16
#define NTH 256

// ---------------- prep kernels ----------------

// dst[k*N + n] = src[n*srcStride + srcOff + k]   (dst is [K][N])
__global__ void transpose_k(const float* __restrict__ src, float* __restrict__ dst,
                            int N, int K, int srcStride, int srcOff) {
  __shared__ float tile[32][33];
  int kb = blockIdx.x * 32, nb = blockIdx.y * 32;
  int tx = threadIdx.x & 31, ty = threadIdx.x >> 5;  // 32 x 8
  for (int r = 0; r < 32; r += 8) {
    int n = nb + ty + r, k = kb + tx;
    if (n < N && k < K) tile[ty + r][tx] = src[(size_t)n * srcStride + srcOff + k];
  }
  __syncthreads();
  for (int r = 0; r < 32; r += 8) {
    int k = kb + ty + r, n = nb + tx;
    if (k < K && n < N) dst[(size_t)k * N + n] = tile[tx][ty + r];
  }
}

// src is [1024][srcStride] row-major; dst[k][j] is float4 with component c = src[c*256 + j][srcOff + k]
// dst flat float4 index = k*256 + j, for k in [0,256), j in [0,256)
__global__ void pack4_k(const float* __restrict__ src, float* __restrict__ dst,
                        int srcStride, int srcOff) {
  int idx = blockIdx.x * blockDim.x + threadIdx.x;
  if (idx >= 256 * 256) return;
  int k = idx >> 8, j = idx & 255;
  float4 v;
  v.x = src[(size_t)(0 * 256 + j) * srcStride + srcOff + k];
  v.y = src[(size_t)(1 * 256 + j) * srcStride + srcOff + k];
  v.z = src[(size_t)(2 * 256 + j) * srcStride + srcOff + k];
  v.w = src[(size_t)(3 * 256 + j) * srcStride + srcOff + k];
  reinterpret_cast<float4*>(dst)[idx] = v;
}

// ptab[tok][n] = sum_e aemb[tok][e] * W_ih0[n][256+e]
__global__ void ptab_k(const float* __restrict__ aemb, const float* __restrict__ Wih0,
                       float* __restrict__ ptab) {
  int n = blockIdx.x * blockDim.x + threadIdx.x;
  if (n >= 1024) return;
  for (int tok = 0; tok < 3; ++tok) {
    float acc = 0.f;
    for (int e = 0; e < E_; ++e)
      acc = fmaf(aemb[tok * E_ + e], Wih0[(size_t)n * 288 + 256 + e], acc);
    ptab[tok * 1024 + n] = acc;
  }
}

// ---------------- main recurrent kernel ----------------

__device__ __forceinline__ float sigmoidf_(float x) { return 1.f / (1.f + expf(-x)); }

// acc[c][b] += sum_k hsrc[b][k] * W[k][tid].c    (W packed as float4 [k*256 + j])
__device__ __forceinline__ void gemm_pass(float acc[4][BT], const float4* __restrict__ W,
                                          const float hsrc[BT][H_], int tid) {
  for (int k = 0; k < H_; k += 4) {
    float4 w0 = W[(k + 0) * 256 + tid];
    float4 w1 = W[(k + 1) * 256 + tid];
    float4 w2 = W[(k + 2) * 256 + tid];
    float4 w3 = W[(k + 3) * 256 + tid];
#pragma unroll
    for (int b = 0; b < BT; ++b) {
      const float4 h = *(const float4*)&hsrc[b][k];
      acc[0][b] = fmaf(h.x, w0.x, acc[0][b]);
      acc[1][b] = fmaf(h.x, w0.y, acc[1][b]);
      acc[2][b] = fmaf(h.x, w0.z, acc[2][b]);
      acc[3][b] = fmaf(h.x, w0.w, acc[3][b]);
      acc[0][b] = fmaf(h.y, w1.x, acc[0][b]);
      acc[1][b] = fmaf(h.y, w1.y, acc[1][b]);
      acc[2][b] = fmaf(h.y, w1.z, acc[2][b]);
      acc[3][b] = fmaf(h.y, w1.w, acc[3][b]);
      acc[0][b] = fmaf(h.z, w2.x, acc[0][b]);
      acc[1][b] = fmaf(h.z, w2.y, acc[1][b]);
      acc[2][b] = fmaf(h.z, w2.z, acc[2][b]);
      acc[3][b] = fmaf(h.z, w2.w, acc[3][b]);
      acc[0][b] = fmaf(h.w, w3.x, acc[0][b]);
      acc[1][b] = fmaf(h.w, w3.y, acc[1][b]);
      acc[2][b] = fmaf(h.w, w3.z, acc[2][b]);
      acc[3][b] = fmaf(h.w, w3.w, acc[3][b]);
    }
  }
}

__global__ __launch_bounds__(NTH, 2)
void actor_main(const float* __restrict__ states,
                const int* __restrict__ actions,
                const float* __restrict__ seWT,   // [S][H]
                const float* __restrict__ se_b,   // [H]
                const float4* __restrict__ W0sP,  // packed [256][256] float4
                const float* __restrict__ b_ih0, const float* __restrict__ b_hh0,
                const float4* __restrict__ Whh0P,
                const float4* __restrict__ Wih1P,
                const float4* __restrict__ Whh1P,
                const float* __restrict__ b_ih1, const float* __restrict__ b_hh1,
                const float* __restrict__ ptab,   // [3][1024]
                const float* __restrict__ headsW, // [D][H][2]
                const float* __restrict__ headsb, // [D][2]
                float* __restrict__ out) {
  __shared__ float h0s[BT][H_];
  __shared__ float h1s[BT][H_];
  __shared__ int acts[BT][D_];
  __shared__ int ptok[BT];

  const int tid = threadIdx.x;
  const int b0 = blockIdx.x * BT;

  // stage states rows into h0s (temp use)
  for (int i = tid; i < BT * S_; i += NTH)
    h0s[i >> 8][i & 255] = states[(size_t)(b0 + (i >> 8)) * S_ + (i & 255)];
  for (int i = tid; i < BT * D_; i += NTH)
    acts[i >> 5][i & 31] = actions[(size_t)(b0 + (i >> 5)) * D_ + (i & 31)];
  if (tid < BT) ptok[tid] = 2;  // START_TOK
  __syncthreads();

  // s_emb = relu(states @ seW.T + se_b) -> h1s (temp use). thread owns col h = tid.
  {
    float acc[BT];
    float bb = se_b[tid];
#pragma unroll
    for (int b = 0; b < BT; ++b) acc[b] = bb;
    for (int s = 0; s < S_; s += 4) {
      float w0 = seWT[(s + 0) * H_ + tid];
      float w1 = seWT[(s + 1) * H_ + tid];
      float w2 = seWT[(s + 2) * H_ + tid];
      float w3 = seWT[(s + 3) * H_ + tid];
#pragma unroll
      for (int b = 0; b < BT; ++b) {
        const float4 hv = *(const float4*)&h0s[b][s];
        acc[b] = fmaf(hv.x, w0, acc[b]);
        acc[b] = fmaf(hv.y, w1, acc[b]);
        acc[b] = fmaf(hv.z, w2, acc[b]);
        acc[b] = fmaf(hv.w, w3, acc[b]);
      }
    }
    __syncthreads();
#pragma unroll
    for (int b = 0; b < BT; ++b) h1s[b][tid] = fmaxf(acc[b], 0.f);
  }
  __syncthreads();

  // x0r[c][b] = b_ih0[n] + b_hh0[n] + s_emb @ W_ih0[:, :256].T   (n = c*256+tid)
  float x0r[4][BT];
  {
#pragma unroll
    for (int c = 0; c < 4; ++c) {
      int n = c * 256 + tid;
      float bias = b_ih0[n] + b_hh0[n];
#pragma unroll
      for (int b = 0; b < BT; ++b) x0r[c][b] = bias;
    }
    gemm_pass(x0r, W0sP, h1s, tid);
  }
  __syncthreads();

  // zero state
  for (int i = tid; i < BT * H_; i += NTH) {
    h0s[i >> 8][i & 255] = 0.f;
    h1s[i >> 8][i & 255] = 0.f;
  }
  float c0r[BT], c1r[BT];
#pragma unroll
  for (int b = 0; b < BT; ++b) { c0r[b] = 0.f; c1r[b] = 0.f; }
  float b1c[4];
#pragma unroll
  for (int c = 0; c < 4; ++c) { int n = c * 256 + tid; b1c[c] = b_ih1[n] + b_hh1[n]; }

  float tlp = 0.f, tent = 0.f;
  const int hb_ = tid >> 4, sub = tid & 15;

  for (int t = 0; t < D_; ++t) {
    __syncthreads();  // prev-step h1s writes + ptok + (t=0) zero-init visible

    // ---- layer 0 gates: acc = x0r + ptab[prev] + h0 @ W_hh0.T
    float acc[4][BT];
#pragma unroll
    for (int b = 0; b < BT; ++b) {
      const float* pt = &ptab[ptok[b] * 1024];
#pragma unroll
      for (int c = 0; c < 4; ++c) acc[c][b] = x0r[c][b] + pt[c * 256 + tid];
    }
    gemm_pass(acc, Whh0P, h0s, tid);

    float h0n[BT];
#pragma unroll
    for (int b = 0; b < BT; ++b) {
      float ig = sigmoidf_(acc[0][b]);
      float fg = sigmoidf_(acc[1][b]);
      float gg = tanhf(acc[2][b]);
      float og = sigmoidf_(acc[3][b]);
      float cn = fg * c0r[b] + ig * gg;
      c0r[b] = cn;
      h0n[b] = og * tanhf(cn);
    }
    __syncthreads();  // all done reading old h0s
#pragma unroll
    for (int b = 0; b < BT; ++b) h0s[b][tid] = h0n[b];
    __syncthreads();  // new h0s visible

    // ---- layer 1 gates: acc = b1 + h0n @ W_ih1.T + h1 @ W_hh1.T
#pragma unroll
    for (int c = 0; c < 4; ++c)
#pragma unroll
      for (int b = 0; b < BT; ++b) acc[c][b] = b1c[c];
    gemm_pass(acc, Wih1P, h0s, tid);
    gemm_pass(acc, Whh1P, h1s, tid);

    float h1n[BT];
#pragma unroll
    for (int b = 0; b < BT; ++b) {
      float ig = sigmoidf_(acc[0][b]);
      float fg = sigmoidf_(acc[1][b]);
      float gg = tanhf(acc[2][b]);
      float og = sigmoidf_(acc[3][b]);
      float cn = fg * c1r[b] + ig * gg;
      c1r[b] = cn;
      h1n[b] = og * tanhf(cn);
    }
    __syncthreads();  // all done reading old h1s
#pragma unroll
    for (int b = 0; b < BT; ++b) h1s[b][tid] = h1n[b];
    __syncthreads();  // new h1s visible

    // ---- heads: logits, log_softmax, entropy. group of 16 threads per row.
    float p0 = 0.f, p1 = 0.f;
    const float* hw = &headsW[t * (H_ * 2)];
#pragma unroll
    for (int jj = 0; jj < 16; ++jj) {
      int j = sub + jj * 16;
      float h = h1s[hb_][j];
      p0 = fmaf(h, hw[j * 2 + 0], p0);
      p1 = fmaf(h, hw[j * 2 + 1], p1);
    }
#pragma unroll
    for (int m = 1; m < 16; m <<= 1) {
      p0 += __shfl_xor(p0, m, 64);
      p1 += __shfl_xor(p1, m, 64);
    }
    float l0 = p0 + headsb[t * 2 + 0], l1 = p1 + headsb[t * 2 + 1];
    float mx = fmaxf(l0, l1);
    float e0 = expf(l0 - mx), e1 = expf(l1 - mx);
    float Z = e0 + e1;
    float lse = mx + logf(Z);
    float lp0 = l0 - lse, lp1 = l1 - lse;
    float ent = -(e0 * lp0 + e1 * lp1) / Z;
    int a = acts[hb_][t];
    float lp = a ? lp1 : lp0;
    if (sub == 0) {
      int row = b0 + hb_;
      out[2 * B_ + (size_t)row * D_ + t] = tlp;  // prefix BEFORE adding this step
      out[2 * B_ + B_ * D_ + (size_t)row * D_ + t] = ent;
      ptok[hb_] = a;
    }
    tlp += lp;
    tent += ent;
  }
  if (sub == 0) {
    int row = b0 + hb_;
    out[row] = tlp;
    out[B_ + row] = tent;
  }
}

// ---------------- launcher ----------------

extern "C" void kernel_launch(void* const* d_in, const int* in_sizes, int n_in,
                              void* d_out, int out_size, void* d_ws, size_t ws_size,
                              hipStream_t stream) {
  const float* states = (const float*)d_in[0];
  const int* actions = (const int*)d_in[1];
  const float* se_W = (const float*)d_in[2];
  const float* se_b = (const float*)d_in[3];
  const float* aemb = (const float*)d_in[4];
  const float* W_ih0 = (const float*)d_in[5];
  const float* W_hh0 = (const float*)d_in[6];
  const float* b_ih0 = (const float*)d_in[7];
  const float* b_hh0 = (const float*)d_in[8];
  const float* W_ih1 = (const float*)d_in[9];
  const float* W_hh1 = (const float*)d_in[10];
  const float* b_ih1 = (const float*)d_in[11];
  const float* b_hh1 = (const float*)d_in[12];
  const float* headsW = (const float*)d_in[13];
  const float* headsb = (const float*)d_in[14];
  float* out = (float*)d_out;
  float* ws = (float*)d_ws;

  float* seWT = ws + 0;           // 65536
  float* W0sP = ws + 65536;       // 262144
  float* Whh0P = ws + 327680;     // 262144
  float* Wih1P = ws + 589824;     // 262144
  float* Whh1P = ws + 851968;     // 262144
  float* ptab = ws + 1114112;     // 3072   (total 1117184 floats = 4.47 MB)

  hipLaunchKernelGGL(transpose_k, dim3(8, 8), dim3(256), 0, stream, se_W, seWT, 256, 256, 256, 0);
  hipLaunchKernelGGL(pack4_k, dim3(256), dim3(256), 0, stream, W_ih0, W0sP, 288, 0);
  hipLaunchKernelGGL(pack4_k, dim3(256), dim3(256), 0, stream, W_hh0, Whh0P, 256, 0);
  hipLaunchKernelGGL(pack4_k, dim3(256), dim3(256), 0, stream, W_ih1, Wih1P, 256, 0);
  hipLaunchKernelGGL(pack4_k, dim3(256), dim3(256), 0, stream, W_hh1, Whh1P, 256, 0);
  hipLaunchKernelGGL(ptab_k, dim3(4), dim3(256), 0, stream, aemb, W_ih0, ptab);
  hipLaunchKernelGGL(actor_main, dim3(B_ / BT), dim3(NTH), 0, stream,
                     states, actions, seWT, se_b, (const float4*)W0sP,
                     b_ih0, b_hh0, (const float4*)Whh0P, (const float4*)Wih1P,
                     (const float4*)Whh1P, b_ih1, b_hh1, ptab, headsW, headsb, out);
}

// Round 3
// 4624.389 us; speedup vs baseline: 1.2824x; 1.2824x over previous
//
#include <hip/hip_runtime.h>
#include <hip/hip_bf16.h>

#define B_ 8192
#define S_ 256
#define D_ 32
#define H_ 256
#define E_ 32
#define BT 32
#define NTH 512

typedef short bf16x8 __attribute__((ext_vector_type(8)));
typedef float f32x4 __attribute__((ext_vector_type(4)));

__device__ __forceinline__ unsigned short f2bf(float x) {
  __hip_bfloat16 h = __float2bfloat16(x);
  return *reinterpret_cast<unsigned short*>(&h);
}
__device__ __forceinline__ float bf2f(unsigned short u) {
  __hip_bfloat16 h = *reinterpret_cast<__hip_bfloat16*>(&u);
  return __bfloat162float(h);
}
__device__ __forceinline__ float sigf_(float x) { return 1.f / (1.f + __expf(-x)); }
__device__ __forceinline__ float tanhf_(float x) {
  float e = __expf(-2.f * fabsf(x));
  float r = (1.f - e) / (1.f + e);
  return copysignf(r, x);
}

// ---------------- prep kernels ----------------

// Pack W [N][srcStride] f32 (cols srcOff..srcOff+255) into mfma B-frag order bf16:
// element (nt,kt,lane,e): n = nt*16+(lane&15), k = kt*32+(lane>>4)*8+e
// flat short index = ((nt*8+kt)*64+lane)*8+e. One thread per 8-elem chunk.
__global__ void packB_k(const float* __restrict__ src, unsigned short* __restrict__ dst,
                        int N, int srcStride, int srcOff) {
  int g = blockIdx.x * blockDim.x + threadIdx.x;
  int total = N * 256 / 8;
  if (g >= total) return;
  int lane = g & 63, kt = (g >> 6) & 7, nt = g >> 9;
  int n = nt * 16 + (lane & 15);
  int k = kt * 32 + (lane >> 4) * 8;
  const float* s = src + (size_t)n * srcStride + srcOff + k;
#pragma unroll
  for (int e = 0; e < 8; ++e) dst[(size_t)g * 8 + e] = f2bf(s[e]);
}

// ptab[tok][n] = sum_e aemb[tok][e] * W_ih0[n][256+e]   (f32)
__global__ void ptab_k(const float* __restrict__ aemb, const float* __restrict__ Wih0,
                       float* __restrict__ ptab) {
  int n = blockIdx.x * blockDim.x + threadIdx.x;
  if (n >= 1024) return;
  for (int tok = 0; tok < 3; ++tok) {
    float acc = 0.f;
    for (int e = 0; e < E_; ++e)
      acc = fmaf(aemb[tok * E_ + e], Wih0[(size_t)n * 288 + 256 + e], acc);
    ptab[tok * 1024 + n] = acc;
  }
}

// bitmask of actions per row
__global__ void actmask_k(const int* __restrict__ a, unsigned* __restrict__ m) {
  int b = blockIdx.x * blockDim.x + threadIdx.x;
  if (b >= B_) return;
  unsigned v = 0;
  for (int t = 0; t < D_; ++t) v |= (unsigned)(a[(size_t)b * D_ + t] & 1) << t;
  m[b] = v;
}

// ---------------- main persistent kernel ----------------

// A/h tile LDS address: [32 rows][256 bf16 cols], byte = row*512 + colbyte, XOR swizzle
__device__ __forceinline__ int haddr(int row, int colbyte) {
  return (row * 512 + colbyte) ^ ((row & 7) << 4);
}

// acc[m][js][g] += A(32x256 from Abuf) x B-slice.  nt = ntBase + g*ntStride + js
template <int NG>
__device__ __forceinline__ void gemm_frag(f32x4 acc[2][2][NG], const unsigned short* __restrict__ Wp,
                                          const char* __restrict__ Abuf, int lane, int ntBase,
                                          int ntStride) {
  const int l15 = lane & 15, l4 = lane >> 4;
#pragma unroll
  for (int kt = 0; kt < 8; ++kt) {
    bf16x8 a[2];
#pragma unroll
    for (int m = 0; m < 2; ++m) {
      int row = m * 16 + l15;
      a[m] = *(const bf16x8*)(Abuf + haddr(row, kt * 64 + l4 * 16));
    }
#pragma unroll
    for (int g = 0; g < NG; ++g) {
#pragma unroll
      for (int js = 0; js < 2; ++js) {
        int nt = ntBase + g * ntStride + js;
        bf16x8 b = *(const bf16x8*)(Wp + (((size_t)nt * 8 + kt) * 64 + lane) * 8);
#pragma unroll
        for (int m = 0; m < 2; ++m)
          acc[m][js][g] = __builtin_amdgcn_mfma_f32_16x16x32_bf16(a[m], b, acc[m][js][g], 0, 0, 0);
      }
    }
  }
}

__global__ __launch_bounds__(NTH, 2)
void actor_main(const float* __restrict__ states,
                const unsigned short* __restrict__ seWP,
                const float* __restrict__ se_b,
                const unsigned short* __restrict__ W0sP,
                const float* __restrict__ b_ih0, const float* __restrict__ b_hh0,
                const unsigned short* __restrict__ Whh0P,
                const unsigned short* __restrict__ Wih1P,
                const unsigned short* __restrict__ Whh1P,
                const float* __restrict__ b_ih1, const float* __restrict__ b_hh1,
                const float* __restrict__ ptabw,   // [3][1024] f32
                const unsigned* __restrict__ amaskw,
                const float* __restrict__ headsW,  // [D][H][2] f32
                const float* __restrict__ headsb,  // [D][2] f32
                float* __restrict__ out) {
  __shared__ char stA[16384];
  __shared__ char h0s[16384];
  __shared__ char h1s[16384];
  __shared__ unsigned amask_s[BT];

  const int tid = threadIdx.x;
  const int lane = tid & 63, wave = tid >> 6;
  const int l15 = lane & 15, l4 = lane >> 4;
  const int b0 = blockIdx.x * BT;
  const int wj = wave * 32;

  // ---- stage states tile -> stA (bf16, A-layout, swizzled)
  {
    int row = tid >> 4, c0i = (tid & 15) * 16;
    const float* sp = states + (size_t)(b0 + row) * S_ + c0i;
    union { unsigned short us[8]; int4 v; } ck0, ck1;
#pragma unroll
    for (int e = 0; e < 8; ++e) ck0.us[e] = f2bf(sp[e]);
#pragma unroll
    for (int e = 0; e < 8; ++e) ck1.us[e] = f2bf(sp[8 + e]);
    *(int4*)(stA + haddr(row, c0i * 2)) = ck0.v;
    *(int4*)(stA + haddr(row, c0i * 2 + 16)) = ck1.v;
  }
  if (tid < BT) amask_s[tid] = amaskw[b0 + tid];
  __syncthreads();

  // ---- s_emb = relu(states @ seW.T + se_b) -> h1s (bf16, swizzled)
  {
    f32x4 acc2[2][2][1];
#pragma unroll
    for (int m = 0; m < 2; ++m)
#pragma unroll
      for (int js = 0; js < 2; ++js) acc2[m][js][0] = (f32x4){0.f, 0.f, 0.f, 0.f};
    gemm_frag<1>(acc2, seWP, stA, lane, wave * 2, 0);
    float seb[2] = {se_b[wj + l15], se_b[wj + 16 + l15]};
#pragma unroll
    for (int m = 0; m < 2; ++m)
#pragma unroll
      for (int js = 0; js < 2; ++js)
#pragma unroll
        for (int r = 0; r < 4; ++r) {
          float v = fmaxf(acc2[m][js][0][r] + seb[js], 0.f);
          int row = m * 16 + l4 * 4 + r, col = wj + js * 16 + l15;
          *(unsigned short*)(h1s + haddr(row, col * 2)) = f2bf(v);
        }
  }
  __syncthreads();

  // ---- x0r = bias + s_emb @ W_ih0[:, :256].T   (persistent registers)
  f32x4 x0r[2][2][4];
  {
    float bias[2][4];
#pragma unroll
    for (int js = 0; js < 2; ++js)
#pragma unroll
      for (int g = 0; g < 4; ++g) {
        int n = g * 256 + wj + js * 16 + l15;
        bias[js][g] = b_ih0[n] + b_hh0[n];
      }
#pragma unroll
    for (int m = 0; m < 2; ++m)
#pragma unroll
      for (int js = 0; js < 2; ++js)
#pragma unroll
        for (int g = 0; g < 4; ++g) {
          float bb = bias[js][g];
          x0r[m][js][g] = (f32x4){bb, bb, bb, bb};
        }
    gemm_frag<4>(x0r, W0sP, h1s, lane, wave * 2, 16);
  }
  __syncthreads();

  // ---- zero h0s/h1s
  for (int i = tid; i < 1024; i += NTH) {
    ((int4*)h0s)[i] = make_int4(0, 0, 0, 0);
    ((int4*)h1s)[i] = make_int4(0, 0, 0, 0);
  }
  __syncthreads();

  // ---- per-thread constants
  float pt[3][2][4], b1b[2][4];
#pragma unroll
  for (int js = 0; js < 2; ++js)
#pragma unroll
    for (int g = 0; g < 4; ++g) {
      int n = g * 256 + wj + js * 16 + l15;
      pt[0][js][g] = ptabw[n];
      pt[1][js][g] = ptabw[1024 + n];
      pt[2][js][g] = ptabw[2048 + n];
      b1b[js][g] = b_ih1[n] + b_hh1[n];
    }
  unsigned am[2][4];
#pragma unroll
  for (int m = 0; m < 2; ++m)
#pragma unroll
    for (int r = 0; r < 4; ++r) am[m][r] = amask_s[m * 16 + l4 * 4 + r];

  float c0v[2][2][4], c1v[2][2][4];
#pragma unroll
  for (int m = 0; m < 2; ++m)
#pragma unroll
    for (int js = 0; js < 2; ++js)
#pragma unroll
      for (int r = 0; r < 4; ++r) { c0v[m][js][r] = 0.f; c1v[m][js][r] = 0.f; }

  const int hrow = wave * 4 + l4;
  const unsigned hmask = amask_s[hrow];
  float tlp = 0.f, tent = 0.f;

#pragma unroll 1
  for (int t = 0; t < D_; ++t) {
    // ==== layer 0: acc = x0r + ptab[tok] + h0 @ Whh0.T
    f32x4 acc[2][2][4];
#pragma unroll
    for (int m = 0; m < 2; ++m)
#pragma unroll
      for (int js = 0; js < 2; ++js)
#pragma unroll
        for (int g = 0; g < 4; ++g)
#pragma unroll
          for (int r = 0; r < 4; ++r) {
            float p;
            if (t == 0) p = pt[2][js][g];
            else p = ((am[m][r] >> (t - 1)) & 1) ? pt[1][js][g] : pt[0][js][g];
            acc[m][js][g][r] = x0r[m][js][g][r] + p;
          }
    gemm_frag<4>(acc, Whh0P, h0s, lane, wave * 2, 16);

    unsigned short hn[2][2][4];
#pragma unroll
    for (int m = 0; m < 2; ++m)
#pragma unroll
      for (int js = 0; js < 2; ++js)
#pragma unroll
        for (int r = 0; r < 4; ++r) {
          float ig = sigf_(acc[m][js][0][r]);
          float fg = sigf_(acc[m][js][1][r]);
          float gg = tanhf_(acc[m][js][2][r]);
          float og = sigf_(acc[m][js][3][r]);
          float c = fg * c0v[m][js][r] + ig * gg;
          c0v[m][js][r] = c;
          hn[m][js][r] = f2bf(og * tanhf_(c));
        }
    __syncthreads();
#pragma unroll
    for (int m = 0; m < 2; ++m)
#pragma unroll
      for (int js = 0; js < 2; ++js)
#pragma unroll
        for (int r = 0; r < 4; ++r) {
          int row = m * 16 + l4 * 4 + r, col = wj + js * 16 + l15;
          *(unsigned short*)(h0s + haddr(row, col * 2)) = hn[m][js][r];
        }
    __syncthreads();

    // ==== layer 1: acc = b1 + h0_new @ Wih1.T + h1_old @ Whh1.T
#pragma unroll
    for (int m = 0; m < 2; ++m)
#pragma unroll
      for (int js = 0; js < 2; ++js)
#pragma unroll
        for (int g = 0; g < 4; ++g) {
          float bb = b1b[js][g];
          acc[m][js][g] = (f32x4){bb, bb, bb, bb};
        }
    gemm_frag<4>(acc, Wih1P, h0s, lane, wave * 2, 16);
    gemm_frag<4>(acc, Whh1P, h1s, lane, wave * 2, 16);

#pragma unroll
    for (int m = 0; m < 2; ++m)
#pragma unroll
      for (int js = 0; js < 2; ++js)
#pragma unroll
        for (int r = 0; r < 4; ++r) {
          float ig = sigf_(acc[m][js][0][r]);
          float fg = sigf_(acc[m][js][1][r]);
          float gg = tanhf_(acc[m][js][2][r]);
          float og = sigf_(acc[m][js][3][r]);
          float c = fg * c1v[m][js][r] + ig * gg;
          c1v[m][js][r] = c;
          hn[m][js][r] = f2bf(og * tanhf_(c));
        }
    __syncthreads();
#pragma unroll
    for (int m = 0; m < 2; ++m)
#pragma unroll
      for (int js = 0; js < 2; ++js)
#pragma unroll
        for (int r = 0; r < 4; ++r) {
          int row = m * 16 + l4 * 4 + r, col = wj + js * 16 + l15;
          *(unsigned short*)(h1s + haddr(row, col * 2)) = hn[m][js][r];
        }
    __syncthreads();

    // ==== heads: 16 lanes per row, row = wave*4 + l4
    float p0 = 0.f, p1 = 0.f;
    const float* hw = headsW + (size_t)t * 512;
#pragma unroll
    for (int jj = 0; jj < 16; ++jj) {
      int j = l15 + jj * 16;
      float h = bf2f(*(const unsigned short*)(h1s + haddr(hrow, j * 2)));
      float2 w = *(const float2*)(hw + j * 2);
      p0 = fmaf(h, w.x, p0);
      p1 = fmaf(h, w.y, p1);
    }
#pragma unroll
    for (int mm = 1; mm < 16; mm <<= 1) {
      p0 += __shfl_xor(p0, mm, 64);
      p1 += __shfl_xor(p1, mm, 64);
    }
    float l0 = p0 + headsb[t * 2 + 0], l1 = p1 + headsb[t * 2 + 1];
    float mx = fmaxf(l0, l1);
    float e0 = __expf(l0 - mx), e1 = __expf(l1 - mx);
    float Z = e0 + e1;
    float lse = mx + __logf(Z);
    float lp0 = l0 - lse, lp1 = l1 - lse;
    float ent = -(e0 * lp0 + e1 * lp1) / Z;
    int a = (hmask >> t) & 1;
    float lp = a ? lp1 : lp0;
    if (l15 == 0) {
      int rowg = b0 + hrow;
      out[2 * B_ + (size_t)rowg * D_ + t] = tlp;  // prefix BEFORE adding
      out[2 * B_ + B_ * D_ + (size_t)rowg * D_ + t] = ent;
    }
    tlp += lp;
    tent += ent;
  }
  if (l15 == 0) {
    int rowg = b0 + hrow;
    out[rowg] = tlp;
    out[B_ + rowg] = tent;
  }
}

// ---------------- launcher ----------------

extern "C" void kernel_launch(void* const* d_in, const int* in_sizes, int n_in,
                              void* d_out, int out_size, void* d_ws, size_t ws_size,
                              hipStream_t stream) {
  const float* states = (const float*)d_in[0];
  const int* actions = (const int*)d_in[1];
  const float* se_W = (const float*)d_in[2];
  const float* se_b = (const float*)d_in[3];
  const float* aemb = (const float*)d_in[4];
  const float* W_ih0 = (const float*)d_in[5];
  const float* W_hh0 = (const float*)d_in[6];
  const float* b_ih0 = (const float*)d_in[7];
  const float* b_hh0 = (const float*)d_in[8];
  const float* W_ih1 = (const float*)d_in[9];
  const float* W_hh1 = (const float*)d_in[10];
  const float* b_ih1 = (const float*)d_in[11];
  const float* b_hh1 = (const float*)d_in[12];
  const float* headsW = (const float*)d_in[13];
  const float* headsb = (const float*)d_in[14];
  float* out = (float*)d_out;
  char* ws = (char*)d_ws;

  unsigned short* seWP  = (unsigned short*)(ws + 0);        // 256*256 bf16 = 131072 B
  unsigned short* W0sP  = (unsigned short*)(ws + 131072);   // 1024*256 bf16 = 524288 B
  unsigned short* Whh0P = (unsigned short*)(ws + 655360);
  unsigned short* Wih1P = (unsigned short*)(ws + 1179648);
  unsigned short* Whh1P = (unsigned short*)(ws + 1703936);
  float* ptabw          = (float*)(ws + 2228224);           // 3*1024 f32 = 12288 B
  unsigned* amaskw      = (unsigned*)(ws + 2240512);        // 8192 u32 = 32768 B

  hipLaunchKernelGGL(packB_k, dim3(32), dim3(256), 0, stream, se_W, seWP, 256, 256, 0);
  hipLaunchKernelGGL(packB_k, dim3(128), dim3(256), 0, stream, W_ih0, W0sP, 1024, 288, 0);
  hipLaunchKernelGGL(packB_k, dim3(128), dim3(256), 0, stream, W_hh0, Whh0P, 1024, 256, 0);
  hipLaunchKernelGGL(packB_k, dim3(128), dim3(256), 0, stream, W_ih1, Wih1P, 1024, 256, 0);
  hipLaunchKernelGGL(packB_k, dim3(128), dim3(256), 0, stream, W_hh1, Whh1P, 1024, 256, 0);
  hipLaunchKernelGGL(ptab_k, dim3(4), dim3(256), 0, stream, aemb, W_ih0, ptabw);
  hipLaunchKernelGGL(actmask_k, dim3(32), dim3(256), 0, stream, actions, amaskw);
  hipLaunchKernelGGL(actor_main, dim3(B_ / BT), dim3(NTH), 0, stream,
                     states, seWP, se_b, W0sP, b_ih0, b_hh0, Whh0P, Wih1P, Whh1P,
                     b_ih1, b_hh1, ptabw, amaskw, headsW, headsb, out);
}

// Round 4
// 3924.437 us; speedup vs baseline: 1.5111x; 1.1784x over previous
//
#include <hip/hip_runtime.h>
#include <hip/hip_bf16.h>

#define B_ 8192
#define S_ 256
#define D_ 32
#define H_ 256
#define E_ 32
#define BT 32
#define NTH 1024

typedef short bf16x8 __attribute__((ext_vector_type(8)));
typedef float f32x4 __attribute__((ext_vector_type(4)));

__device__ __forceinline__ unsigned short f2bf(float x) {
  __hip_bfloat16 h = __float2bfloat16(x);
  return *reinterpret_cast<unsigned short*>(&h);
}
__device__ __forceinline__ unsigned pack2bf(float a, float b) {
  return (unsigned)f2bf(a) | ((unsigned)f2bf(b) << 16);
}
__device__ __forceinline__ float lo_bf(unsigned u) { return __uint_as_float(u << 16); }
__device__ __forceinline__ float hi_bf(unsigned u) { return __uint_as_float(u & 0xffff0000u); }
__device__ __forceinline__ float bf2f(unsigned short u) {
  return __uint_as_float((unsigned)u << 16);
}
__device__ __forceinline__ float sigf_(float x) { return 1.f / (1.f + __expf(-x)); }
__device__ __forceinline__ float tanhf_(float x) {
  float e = __expf(-2.f * fabsf(x));
  float r = (1.f - e) / (1.f + e);
  return copysignf(r, x);
}

// ---------------- prep kernels ----------------

// Pack W [N][srcStride] f32 (cols srcOff..+255) into mfma B-frag order bf16:
// n = nt*16+(lane&15), k = kt*32+(lane>>4)*8+e; flat = ((nt*8+kt)*64+lane)*8+e
__global__ void packB_k(const float* __restrict__ src, unsigned short* __restrict__ dst,
                        int N, int srcStride, int srcOff) {
  int g = blockIdx.x * blockDim.x + threadIdx.x;
  int total = N * 256 / 8;
  if (g >= total) return;
  int lane = g & 63, kt = (g >> 6) & 7, nt = g >> 9;
  int n = nt * 16 + (lane & 15);
  int k = kt * 32 + (lane >> 4) * 8;
  const float* s = src + (size_t)n * srcStride + srcOff + k;
#pragma unroll
  for (int e = 0; e < 8; ++e) dst[(size_t)g * 8 + e] = f2bf(s[e]);
}

// ptab[tok][n] = sum_e aemb[tok][e] * W_ih0[n][256+e]
__global__ void ptab_k(const float* __restrict__ aemb, const float* __restrict__ Wih0,
                       float* __restrict__ ptab) {
  int n = blockIdx.x * blockDim.x + threadIdx.x;
  if (n >= 1024) return;
  for (int tok = 0; tok < 3; ++tok) {
    float acc = 0.f;
    for (int e = 0; e < E_; ++e)
      acc = fmaf(aemb[tok * E_ + e], Wih0[(size_t)n * 288 + 256 + e], acc);
    ptab[tok * 1024 + n] = acc;
  }
}

__global__ void actmask_k(const int* __restrict__ a, unsigned* __restrict__ m) {
  int b = blockIdx.x * blockDim.x + threadIdx.x;
  if (b >= B_) return;
  unsigned v = 0;
  for (int t = 0; t < D_; ++t) v |= (unsigned)(a[(size_t)b * D_ + t] & 1) << t;
  m[b] = v;
}

// ---------------- main persistent kernel ----------------

// h tile LDS address: [32 rows][256 bf16 cols], byte = row*512 + colbyte, XOR swizzle
__device__ __forceinline__ int haddr(int row, int colbyte) {
  return (row * 512 + colbyte) ^ ((row & 7) << 4);
}

// acc[m][g] += A(32x256 from Abuf) x B(nt = g*16 + wave).
// Wlane = Wp + wave*4096 + lane*8 (shorts). g-offset = 65536 shorts, kt-offset = 512.
template <int NG>
__device__ __forceinline__ void gemm_frag(f32x4 acc[2][NG], const unsigned short* __restrict__ Wlane,
                                          const char* __restrict__ Abuf, int l15, int l4) {
#pragma unroll
  for (int kt = 0; kt < 8; ++kt) {
    bf16x8 a0 = *(const bf16x8*)(Abuf + haddr(l15, kt * 64 + l4 * 16));
    bf16x8 a1 = *(const bf16x8*)(Abuf + haddr(16 + l15, kt * 64 + l4 * 16));
#pragma unroll
    for (int g = 0; g < NG; ++g) {
      bf16x8 b = *(const bf16x8*)(Wlane + g * 65536 + kt * 512);
      acc[0][g] = __builtin_amdgcn_mfma_f32_16x16x32_bf16(a0, b, acc[0][g], 0, 0, 0);
      acc[1][g] = __builtin_amdgcn_mfma_f32_16x16x32_bf16(a1, b, acc[1][g], 0, 0, 0);
    }
  }
}

__global__ __launch_bounds__(NTH)
void actor_main(const float* __restrict__ states,
                const unsigned short* __restrict__ seWP,
                const float* __restrict__ se_b,
                const unsigned short* __restrict__ W0sP,
                const float* __restrict__ b_ih0, const float* __restrict__ b_hh0,
                const unsigned short* __restrict__ Whh0P,
                const unsigned short* __restrict__ Wih1P,
                const unsigned short* __restrict__ Whh1P,
                const float* __restrict__ b_ih1, const float* __restrict__ b_hh1,
                const float* __restrict__ ptabw,   // [3][1024] f32
                const unsigned* __restrict__ amaskw,
                const float* __restrict__ headsW,  // [D][H][2] f32
                const float* __restrict__ headsb,  // [D][2] f32
                float* __restrict__ out) {
  __shared__ char stA[16384];
  __shared__ char h0s[16384];
  __shared__ char h1s[16384];
  __shared__ unsigned amask_s[BT];

  const int tid = threadIdx.x;
  const int lane = tid & 63, wave = tid >> 6;
  const int l15 = lane & 15, l4 = lane >> 4;
  const int b0 = blockIdx.x * BT;
  const int wbase = wave * 4096 + lane * 8;  // shorts, per-matrix lane base

  // ---- stage states tile -> stA (bf16, A-layout, swizzled). threads 0..511.
  if (tid < 512) {
    int row = tid >> 4, c0i = (tid & 15) * 16;
    const float* sp = states + (size_t)(b0 + row) * S_ + c0i;
    union { unsigned short us[8]; int4 v; } ck0, ck1;
#pragma unroll
    for (int e = 0; e < 8; ++e) ck0.us[e] = f2bf(sp[e]);
#pragma unroll
    for (int e = 0; e < 8; ++e) ck1.us[e] = f2bf(sp[8 + e]);
    *(int4*)(stA + haddr(row, c0i * 2)) = ck0.v;
    *(int4*)(stA + haddr(row, c0i * 2 + 16)) = ck1.v;
  }
  if (tid < BT) amask_s[tid] = amaskw[b0 + tid];
  __syncthreads();

  // ---- s_emb = relu(states @ seW.T + se_b) -> h1s.  wave w owns cols w*16..w*16+15.
  {
    f32x4 a1[2][1];
#pragma unroll
    for (int m = 0; m < 2; ++m) a1[m][0] = (f32x4){0.f, 0.f, 0.f, 0.f};
    gemm_frag<1>(a1, seWP + wbase, stA, l15, l4);
    float seb = se_b[wave * 16 + l15];
#pragma unroll
    for (int m = 0; m < 2; ++m)
#pragma unroll
      for (int r = 0; r < 4; ++r) {
        float v = fmaxf(a1[m][0][r] + seb, 0.f);
        *(unsigned short*)(h1s + haddr(m * 16 + l4 * 4 + r, (wave * 16 + l15) * 2)) = f2bf(v);
      }
  }
  __syncthreads();

  // ---- x0 = bias0 + s_emb @ W_ih0[:, :256].T  -> packed bf16 in 16 regs
  unsigned x0p[2][4][2];
  {
    f32x4 xa[2][4];
#pragma unroll
    for (int m = 0; m < 2; ++m)
#pragma unroll
      for (int g = 0; g < 4; ++g) xa[m][g] = (f32x4){0.f, 0.f, 0.f, 0.f};
    gemm_frag<4>(xa, W0sP + wbase, h1s, l15, l4);
#pragma unroll
    for (int g = 0; g < 4; ++g) {
      int n = g * 256 + wave * 16 + l15;
      float bias = b_ih0[n] + b_hh0[n];
#pragma unroll
      for (int m = 0; m < 2; ++m) {
        x0p[m][g][0] = pack2bf(xa[m][g][0] + bias, xa[m][g][1] + bias);
        x0p[m][g][1] = pack2bf(xa[m][g][2] + bias, xa[m][g][3] + bias);
      }
    }
  }
  __syncthreads();

  // ---- zero h0s/h1s
  for (int i = tid; i < 2048; i += NTH) {
    ((int4*)h0s)[i & 1023] = make_int4(0, 0, 0, 0);
    if (i >= 1024) ((int4*)h1s)[i & 1023] = make_int4(0, 0, 0, 0);
  }
  __syncthreads();

  // ---- packed per-thread constants
  unsigned ptp[3][2], b1p[2];
#pragma unroll
  for (int tok = 0; tok < 3; ++tok)
#pragma unroll
    for (int j = 0; j < 2; ++j) {
      int n0 = (2 * j) * 256 + wave * 16 + l15, n1 = (2 * j + 1) * 256 + wave * 16 + l15;
      ptp[tok][j] = pack2bf(ptabw[tok * 1024 + n0], ptabw[tok * 1024 + n1]);
    }
#pragma unroll
  for (int j = 0; j < 2; ++j) {
    int n0 = (2 * j) * 256 + wave * 16 + l15, n1 = (2 * j + 1) * 256 + wave * 16 + l15;
    b1p[j] = pack2bf(b_ih1[n0] + b_hh1[n0], b_ih1[n1] + b_hh1[n1]);
  }
  float b1g[4] = {lo_bf(b1p[0]), hi_bf(b1p[0]), lo_bf(b1p[1]), hi_bf(b1p[1])};

  float c0v[2][4], c1v[2][4];
#pragma unroll
  for (int m = 0; m < 2; ++m)
#pragma unroll
    for (int r = 0; r < 4; ++r) { c0v[m][r] = 0.f; c1v[m][r] = 0.f; }

  const int hrow = wave * 2 + (lane >> 5);
  const int l31 = lane & 31;
  const unsigned hmask = amask_s[hrow];
  float tlp = 0.f, tent = 0.f;

#pragma unroll 1
  for (int t = 0; t < D_; ++t) {
    // unpack ptab values for this step's token choices
    float p0g[4], p1g[4];
    if (t == 0) {
#pragma unroll
      for (int j = 0; j < 2; ++j) {
        p0g[2 * j] = lo_bf(ptp[2][j]); p0g[2 * j + 1] = hi_bf(ptp[2][j]);
        p1g[2 * j] = p0g[2 * j];       p1g[2 * j + 1] = p0g[2 * j + 1];
      }
    } else {
#pragma unroll
      for (int j = 0; j < 2; ++j) {
        p0g[2 * j] = lo_bf(ptp[0][j]); p0g[2 * j + 1] = hi_bf(ptp[0][j]);
        p1g[2 * j] = lo_bf(ptp[1][j]); p1g[2 * j + 1] = hi_bf(ptp[1][j]);
      }
    }

    // ==== layer 0: acc = x0 + ptab[tok] + h0 @ Whh0.T
    f32x4 acc[2][4];
#pragma unroll
    for (int m = 0; m < 2; ++m)
#pragma unroll
      for (int r = 0; r < 4; ++r) {
        unsigned msk = amask_s[m * 16 + l4 * 4 + r];  // LDS broadcast read
        bool hi1 = t ? (((msk >> (t - 1)) & 1u) != 0u) : false;
#pragma unroll
        for (int g = 0; g < 4; ++g) {
          float x0v = (r & 1) ? hi_bf(x0p[m][g][r >> 1]) : lo_bf(x0p[m][g][r >> 1]);
          acc[m][g][r] = x0v + (hi1 ? p1g[g] : p0g[g]);
        }
      }
    gemm_frag<4>(acc, Whh0P + wbase, h0s, l15, l4);

    unsigned short hn[2][4];
#pragma unroll
    for (int m = 0; m < 2; ++m)
#pragma unroll
      for (int r = 0; r < 4; ++r) {
        float ig = sigf_(acc[m][0][r]);
        float fg = sigf_(acc[m][1][r]);
        float gg = tanhf_(acc[m][2][r]);
        float og = sigf_(acc[m][3][r]);
        float c = fg * c0v[m][r] + ig * gg;
        c0v[m][r] = c;
        hn[m][r] = f2bf(og * tanhf_(c));
      }
    __syncthreads();  // everyone done reading old h0s
#pragma unroll
    for (int m = 0; m < 2; ++m)
#pragma unroll
      for (int r = 0; r < 4; ++r)
        *(unsigned short*)(h0s + haddr(m * 16 + l4 * 4 + r, (wave * 16 + l15) * 2)) = hn[m][r];
    __syncthreads();  // new h0s visible

    // ==== layer 1: acc = b1 + h0_new @ Wih1.T + h1_old @ Whh1.T
#pragma unroll
    for (int m = 0; m < 2; ++m)
#pragma unroll
      for (int g = 0; g < 4; ++g) {
        float bb = b1g[g];
        acc[m][g] = (f32x4){bb, bb, bb, bb};
      }
    gemm_frag<4>(acc, Wih1P + wbase, h0s, l15, l4);
    gemm_frag<4>(acc, Whh1P + wbase, h1s, l15, l4);

#pragma unroll
    for (int m = 0; m < 2; ++m)
#pragma unroll
      for (int r = 0; r < 4; ++r) {
        float ig = sigf_(acc[m][0][r]);
        float fg = sigf_(acc[m][1][r]);
        float gg = tanhf_(acc[m][2][r]);
        float og = sigf_(acc[m][3][r]);
        float c = fg * c1v[m][r] + ig * gg;
        c1v[m][r] = c;
        hn[m][r] = f2bf(og * tanhf_(c));
      }
    __syncthreads();  // everyone done reading old h1s
#pragma unroll
    for (int m = 0; m < 2; ++m)
#pragma unroll
      for (int r = 0; r < 4; ++r)
        *(unsigned short*)(h1s + haddr(m * 16 + l4 * 4 + r, (wave * 16 + l15) * 2)) = hn[m][r];
    __syncthreads();  // new h1s visible

    // ==== heads: 32 lanes per row, row = wave*2 + (lane>>5)
    float p0 = 0.f, p1 = 0.f;
    const float* hw = headsW + (size_t)t * 512;
#pragma unroll
    for (int jj = 0; jj < 8; ++jj) {
      int j = l31 + jj * 32;
      float h = bf2f(*(const unsigned short*)(h1s + haddr(hrow, j * 2)));
      float2 w = *(const float2*)(hw + j * 2);
      p0 = fmaf(h, w.x, p0);
      p1 = fmaf(h, w.y, p1);
    }
#pragma unroll
    for (int mm = 1; mm < 32; mm <<= 1) {
      p0 += __shfl_xor(p0, mm, 64);
      p1 += __shfl_xor(p1, mm, 64);
    }
    float l0 = p0 + headsb[t * 2 + 0], l1 = p1 + headsb[t * 2 + 1];
    float mx = fmaxf(l0, l1);
    float e0 = __expf(l0 - mx), e1 = __expf(l1 - mx);
    float Z = e0 + e1;
    float lse = mx + __logf(Z);
    float lp0 = l0 - lse, lp1 = l1 - lse;
    float ent = -(e0 * lp0 + e1 * lp1) / Z;
    int a = (hmask >> t) & 1;
    float lp = a ? lp1 : lp0;
    if (l31 == 0) {
      int rowg = b0 + hrow;
      out[2 * B_ + (size_t)rowg * D_ + t] = tlp;  // prefix BEFORE adding
      out[2 * B_ + B_ * D_ + (size_t)rowg * D_ + t] = ent;
    }
    tlp += lp;
    tent += ent;
  }
  if (l31 == 0) {
    int rowg = b0 + hrow;
    out[rowg] = tlp;
    out[B_ + rowg] = tent;
  }
}

// ---------------- launcher ----------------

extern "C" void kernel_launch(void* const* d_in, const int* in_sizes, int n_in,
                              void* d_out, int out_size, void* d_ws, size_t ws_size,
                              hipStream_t stream) {
  const float* states = (const float*)d_in[0];
  const int* actions = (const int*)d_in[1];
  const float* se_W = (const float*)d_in[2];
  const float* se_b = (const float*)d_in[3];
  const float* aemb = (const float*)d_in[4];
  const float* W_ih0 = (const float*)d_in[5];
  const float* W_hh0 = (const float*)d_in[6];
  const float* b_ih0 = (const float*)d_in[7];
  const float* b_hh0 = (const float*)d_in[8];
  const float* W_ih1 = (const float*)d_in[9];
  const float* W_hh1 = (const float*)d_in[10];
  const float* b_ih1 = (const float*)d_in[11];
  const float* b_hh1 = (const float*)d_in[12];
  const float* headsW = (const float*)d_in[13];
  const float* headsb = (const float*)d_in[14];
  float* out = (float*)d_out;
  char* ws = (char*)d_ws;

  unsigned short* seWP  = (unsigned short*)(ws + 0);        // 131072 B
  unsigned short* W0sP  = (unsigned short*)(ws + 131072);   // 524288 B each
  unsigned short* Whh0P = (unsigned short*)(ws + 655360);
  unsigned short* Wih1P = (unsigned short*)(ws + 1179648);
  unsigned short* Whh1P = (unsigned short*)(ws + 1703936);
  float* ptabw          = (float*)(ws + 2228224);
  unsigned* amaskw      = (unsigned*)(ws + 2240512);

  hipLaunchKernelGGL(packB_k, dim3(32), dim3(256), 0, stream, se_W, seWP, 256, 256, 0);
  hipLaunchKernelGGL(packB_k, dim3(128), dim3(256), 0, stream, W_ih0, W0sP, 1024, 288, 0);
  hipLaunchKernelGGL(packB_k, dim3(128), dim3(256), 0, stream, W_hh0, Whh0P, 1024, 256, 0);
  hipLaunchKernelGGL(packB_k, dim3(128), dim3(256), 0, stream, W_ih1, Wih1P, 1024, 256, 0);
  hipLaunchKernelGGL(packB_k, dim3(128), dim3(256), 0, stream, W_hh1, Whh1P, 1024, 256, 0);
  hipLaunchKernelGGL(ptab_k, dim3(4), dim3(256), 0, stream, aemb, W_ih0, ptabw);
  hipLaunchKernelGGL(actmask_k, dim3(32), dim3(256), 0, stream, actions, amaskw);
  hipLaunchKernelGGL(actor_main, dim3(B_ / BT), dim3(NTH), 0, stream,
                     states, seWP, se_b, W0sP, b_ih0, b_hh0, Whh0P, Wih1P, Whh1P,
                     b_ih1, b_hh1, ptabw, amaskw, headsW, headsb, out);
}